// Round 1
// 649.392 us; speedup vs baseline: 1.0271x; 1.0271x over previous
//
#include <hip/hip_runtime.h>
#include <stdint.h>

// Problem constants (match reference)
#define NUM_STEPS  256
#define INPUT_SIZE 784
#define N_NEURONS  512
// 784 cols = 196 float4-chunks. One WAVE (64 lanes) per neuron row:
// lane owns chunks {lane, lane+64, lane+128}; lanes 0..3 also own chunk 192+lane.
// All global loads/stores are contiguous across lanes (3x1KB + 64B per step, fp32).

// bf16 <-> fp32 helpers (bit-exact widen; RNE narrow)
__device__ __forceinline__ float bf2f(unsigned short u) {
    union { uint32_t i; float f; } v; v.i = ((uint32_t)u) << 16; return v.f;
}
__device__ __forceinline__ unsigned short f2bf(float f) {
    union { float f; uint32_t i; } v; v.f = f;
    uint32_t x = v.i;
    return (unsigned short)((x + 0x7fffu + ((x >> 16) & 1u)) >> 16);
}

template <bool F32>
__device__ __forceinline__ void ld_chunk(const void* __restrict__ base, size_t elem, float* d) {
    if constexpr (F32) {
        const float4 v = *(const float4*)((const float*)base + elem);
        d[0] = v.x; d[1] = v.y; d[2] = v.z; d[3] = v.w;
    } else {
        const ushort4 v = *(const ushort4*)((const unsigned short*)base + elem);
        d[0] = bf2f(v.x); d[1] = bf2f(v.y); d[2] = bf2f(v.z); d[3] = bf2f(v.w);
    }
}

template <bool F32>
__device__ __forceinline__ void st_chunk(void* __restrict__ base, size_t elem, const float* s) {
    if constexpr (F32) {
        *(float4*)((float*)base + elem) = make_float4(s[0], s[1], s[2], s[3]);
    } else {
        ushort4 v;
        v.x = f2bf(s[0]); v.y = f2bf(s[1]); v.z = f2bf(s[2]); v.w = f2bf(s[3]);
        *(ushort4*)((unsigned short*)base + elem) = v;
    }
}

// One wave per neuron row. The full 256-step scan runs inside the wave:
// per step: (prefetch x_{t+1}) -> per-lane partial dot -> 6-step shfl_xor
// butterfly all-reduce (no LDS, no barrier!) -> wave-uniform scalar LIF ->
// STDP weight update + clamp -> coalesced store. Stores are never drained by
// a barrier-vmcnt(0): the only vmcnt waits are for the x prefetch, which is
// issued BEFORE the stores each step, so step-t stores get a full step in
// flight before anything forces their retirement (in-order vmcnt).
template <bool F32>
__device__ void scan_run(const void* __restrict__ img_v,
                         const void* __restrict__ W_v,
                         void* __restrict__ out_v)
{
    const int row  = blockIdx.x;
    const int lane = threadIdx.x;          // 64 threads = exactly 1 wave
    const bool has4 = lane < 4;

    const size_t WREC = (size_t)NUM_STEPS * N_NEURONS * INPUT_SIZE;
    const size_t SREC = (size_t)NUM_STEPS * N_NEURONS;

    // element offsets of this lane's chunks within a 784-element row
    size_t cofs[4];
    cofs[0] = (size_t)(lane      ) * 4;
    cofs[1] = (size_t)(lane +  64) * 4;
    cofs[2] = (size_t)(lane + 128) * 4;
    cofs[3] = (size_t)(192 + lane) * 4;    // only meaningful for lane < 4

    float w[4][4], p[4][4], x[4][4], xn[4][4];
    #pragma unroll
    for (int c = 0; c < 4; ++c)
        #pragma unroll
        for (int j = 0; j < 4; ++j) { w[c][j] = 0.f; p[c][j] = 0.f; x[c][j] = 0.f; xn[c][j] = 0.f; }

    {
        const size_t wbase = (size_t)row * INPUT_SIZE;
        #pragma unroll
        for (int c = 0; c < 3; ++c) ld_chunk<F32>(W_v, wbase + cofs[c], w[c]);
        if (has4) ld_chunk<F32>(W_v, wbase + cofs[3], w[3]);
        // preload x for t = 0
        #pragma unroll
        for (int c = 0; c < 3; ++c) ld_chunk<F32>(img_v, cofs[c], x[c]);
        if (has4) ld_chunk<F32>(img_v, cofs[3], x[3]);
    }

    float syn = 0.f, mem = 0.f, spk_prev = 0.f, post = 0.f;

    for (int t = 0; t < NUM_STEPS; ++t) {
        // prefetch next image row FIRST (so later waits on it don't drain this
        // step's stores; stores are issued after these loads in program order)
        if (t + 1 < NUM_STEPS) {
            const size_t xbase = (size_t)(t + 1) * INPUT_SIZE;
            #pragma unroll
            for (int c = 0; c < 3; ++c) ld_chunk<F32>(img_v, xbase + cofs[c], xn[c]);
            if (has4) ld_chunk<F32>(img_v, xbase + cofs[3], xn[3]);
        }

        // per-lane partial dot product (lanes >=4 have w[3]=x[3]=0)
        float partial = 0.f;
        #pragma unroll
        for (int c = 0; c < 4; ++c)
            #pragma unroll
            for (int j = 0; j < 4; ++j) partial += w[c][j] * x[c][j];

        // 64-lane butterfly all-reduce: every lane ends with the full sum
        #pragma unroll
        for (int off = 1; off < 64; off <<= 1)
            partial += __shfl_xor(partial, off, 64);
        const float I = partial;

        // LIF scalar state (wave-uniform, computed redundantly in every lane)
        syn = 0.9f * syn + I;                       // ALPHA
        mem = 0.8f * mem + syn - spk_prev;          // BETA, subtract-reset (THRESHOLD=1)
        const float spk = (mem > 1.0f) ? 1.0f : 0.0f;
        post = 0.9f * post + spk;                   // BETA_MINUS
        const float ap = 0.008f  * spk;             // A_PLUS  * spk
        const float am = 0.0066f * post;            // A_MINUS * post

        const size_t r     = (size_t)t * N_NEURONS + row;
        const size_t obase = r * INPUT_SIZE;

        // STDP update + clamp (pre-trace BEFORE its recurrence update)
        #pragma unroll
        for (int c = 0; c < 4; ++c)
            #pragma unroll
            for (int j = 0; j < 4; ++j)
                w[c][j] = fminf(fmaxf(w[c][j] + ap * p[c][j] - am * x[c][j], 0.f), 1.f);

        #pragma unroll
        for (int c = 0; c < 3; ++c) st_chunk<F32>(out_v, obase + cofs[c], w[c]);
        if (has4) st_chunk<F32>(out_v, obase + cofs[3], w[3]);

        if (lane == 0) {
            if constexpr (F32) {
                float* out = (float*)out_v;
                out[WREC + 0 * SREC + r] = spk;
                out[WREC + 1 * SREC + r] = mem;
                out[WREC + 2 * SREC + r] = syn;
                out[WREC + 3 * SREC + r] = post;
            } else {
                unsigned short* out = (unsigned short*)out_v;
                out[WREC + 0 * SREC + r] = f2bf(spk);
                out[WREC + 1 * SREC + r] = f2bf(mem);
                out[WREC + 2 * SREC + r] = f2bf(syn);
                out[WREC + 3 * SREC + r] = f2bf(post);
            }
        }

        // pre-trace recurrence + rotate prefetched x into place
        #pragma unroll
        for (int c = 0; c < 4; ++c)
            #pragma unroll
            for (int j = 0; j < 4; ++j) {
                p[c][j] = 0.9f * p[c][j] + x[c][j];
                x[c][j] = xn[c][j];
            }
        spk_prev = spk;
    }
}

__global__ __launch_bounds__(64) void snn_row_scan_kernel(
    const void* __restrict__ img,
    const void* __restrict__ W,
    void* __restrict__ out)
{
    // Runtime dtype sniff (wave-uniform): bf16 data in [0,1] never has a
    // 16-bit halfword > 0x3F80; fp32 data's low halfwords are random mantissa
    // bits. All threads read the same 256 bytes -> branch is uniform.
    const unsigned short* w16 = (const unsigned short*)W;
    bool f32 = false;
    for (int i = 0; i < 128; ++i) f32 |= (w16[i] > 0x3F80u);
    if (f32) scan_run<true >(img, W, out);
    else     scan_run<false>(img, W, out);
}

extern "C" void kernel_launch(void* const* d_in, const int* in_sizes, int n_in,
                              void* d_out, int out_size, void* d_ws, size_t ws_size,
                              hipStream_t stream) {
    (void)in_sizes; (void)n_in; (void)d_ws; (void)ws_size; (void)out_size;
    snn_row_scan_kernel<<<dim3(N_NEURONS), dim3(64), 0, stream>>>(d_in[0], d_in[1], d_out);
}

// Round 2
// 557.881 us; speedup vs baseline: 1.1955x; 1.1640x over previous
//
#include <hip/hip_runtime.h>
#include <stdint.h>

// Problem constants (match reference)
#define NUM_STEPS  256
#define INPUT_SIZE 784
#define N_NEURONS  512

typedef float    v4f __attribute__((ext_vector_type(4)));
typedef uint16_t v4h __attribute__((ext_vector_type(4)));

// bf16 <-> fp32 helpers (bit-exact widen; RNE narrow)
__device__ __forceinline__ float bf2f(unsigned short u) {
    union { uint32_t i; float f; } v; v.i = ((uint32_t)u) << 16; return v.f;
}
__device__ __forceinline__ unsigned short f2bf(float f) {
    union { float f; uint32_t i; } v; v.f = f;
    uint32_t x = v.i;
    return (unsigned short)((x + 0x7fffu + ((x >> 16) & 1u)) >> 16);
}

template <bool F32>
__device__ __forceinline__ void ld_chunk(const void* __restrict__ base, size_t elem, float* d) {
    if constexpr (F32) {
        const v4f v = *(const v4f*)((const float*)base + elem);
        d[0] = v.x; d[1] = v.y; d[2] = v.z; d[3] = v.w;
    } else {
        const v4h v = *(const v4h*)((const unsigned short*)base + elem);
        d[0] = bf2f(v.x); d[1] = bf2f(v.y); d[2] = bf2f(v.z); d[3] = bf2f(v.w);
    }
}

// Non-temporal store of one 4-element chunk (write-once 430MB stream: skip L2).
template <bool F32>
__device__ __forceinline__ void st_chunk_nt(void* __restrict__ base, size_t elem, const float* s) {
    if constexpr (F32) {
        v4f v; v.x = s[0]; v.y = s[1]; v.z = s[2]; v.w = s[3];
        __builtin_nontemporal_store(v, (v4f*)((float*)base + elem));
    } else {
        v4h v; v.x = f2bf(s[0]); v.y = f2bf(s[1]); v.z = f2bf(s[2]); v.w = f2bf(s[3]);
        __builtin_nontemporal_store(v, (v4h*)((unsigned short*)base + elem));
    }
}

// One wave per neuron row, 2 rows (2 waves) per block sharing the LDS image
// bitmask. Pre-pass: pack the binary image (Bernoulli 0/1 spikes) into LDS as
// 16 bits/lane/step (uint2[64][64] = 32KB = all 256 steps). Main loop:
//   - NO global loads (masks via ds_read_b64 -> lgkm domain only)
//   - weight regs rotate through 4 named buffers so a store's source regs are
//     not redefined for 4 steps (no WAR-forced waits on young stores)
//   - scalar state staged in LDS, dumped once per 64 steps
//   - W_rec stores are fire-and-forget nontemporal; nothing in the loop ever
//     waits on vmcnt, so stores pipeline ~5 steps deep (HW 64-entry queue).
template <bool F32>
__device__ void scan_run(const void* __restrict__ img_v,
                         const void* __restrict__ W_v,
                         void* __restrict__ out_v,
                         uint2 (&msk)[64][64],
                         float (&sbuf)[2][64][4])
{
    const int tid  = threadIdx.x;
    const int wid  = tid >> 6;
    const int lane = tid & 63;
    const int row  = (blockIdx.x << 1) | wid;
    const bool has4 = lane < 4;

    const size_t WREC = (size_t)NUM_STEPS * N_NEURONS * INPUT_SIZE;
    const size_t SREC = (size_t)NUM_STEPS * N_NEURONS;

    // element offsets of this lane's chunks within a 784-element row
    size_t cofs[4];
    cofs[0] = (size_t)(lane      ) * 4;
    cofs[1] = (size_t)(lane +  64) * 4;
    cofs[2] = (size_t)(lane + 128) * 4;
    cofs[3] = (size_t)(192 + lane) * 4;   // lanes 0..3 only

    // ---- pre-pass: pack image spike bits into LDS (split across 2 waves) ----
    for (int i = wid; i < 64; i += 2) {          // i indexes groups of 4 steps
        uint32_t lo = 0, hi = 0;
        #pragma unroll
        for (int s = 0; s < 4; ++s) {
            const int t = 4 * i + s;
            float a[4][4] = {};
            const size_t xb = (size_t)t * INPUT_SIZE;
            ld_chunk<F32>(img_v, xb + cofs[0], a[0]);
            ld_chunk<F32>(img_v, xb + cofs[1], a[1]);
            ld_chunk<F32>(img_v, xb + cofs[2], a[2]);
            if (has4) ld_chunk<F32>(img_v, xb + cofs[3], a[3]);
            uint32_t m = 0;
            #pragma unroll
            for (int c = 0; c < 4; ++c)
                #pragma unroll
                for (int j = 0; j < 4; ++j)
                    m |= (uint32_t)(a[c][j] != 0.0f) << (4 * c + j);
            if      (s == 0) lo  = m;
            else if (s == 1) lo |= m << 16;
            else if (s == 2) hi  = m;
            else             hi |= m << 16;
        }
        msk[i][lane] = make_uint2(lo, hi);
    }

    // ---- weight row into registers (buffer 0 of the 4-deep rotation) ----
    float wb0[16], wb1[16], wb2[16], wb3[16], p[16];
    #pragma unroll
    for (int k = 0; k < 16; ++k) { wb0[k] = 0.f; wb1[k] = 0.f; wb2[k] = 0.f; wb3[k] = 0.f; p[k] = 0.f; }
    {
        const size_t wbase = (size_t)row * INPUT_SIZE;
        ld_chunk<F32>(W_v, wbase + cofs[0], &wb0[0]);
        ld_chunk<F32>(W_v, wbase + cofs[1], &wb0[4]);
        ld_chunk<F32>(W_v, wbase + cofs[2], &wb0[8]);
        if (has4) ld_chunk<F32>(W_v, wbase + cofs[3], &wb0[12]);
    }

    __syncthreads();   // masks visible across the 2 waves (only barrier in kernel)

    float syn = 0.f, mem = 0.f, spk_prev = 0.f, post = 0.f;
    int t = 0;

#define STEP(WI, WO, MB) do {                                                   \
        const uint32_t mb_ = (MB);                                              \
        float xf[16];                                                           \
        _Pragma("unroll")                                                       \
        for (int k = 0; k < 16; ++k) xf[k] = ((mb_ >> k) & 1u) ? 1.0f : 0.0f;   \
        /* dot product, explicit shallow tree */                                \
        float g[8];                                                             \
        _Pragma("unroll")                                                       \
        for (int k = 0; k < 8; ++k)                                             \
            g[k] = WI[2*k] * xf[2*k] + WI[2*k+1] * xf[2*k+1];                   \
        const float h0_ = (g[0] + g[1]) + (g[2] + g[3]);                        \
        const float h1_ = (g[4] + g[5]) + (g[6] + g[7]);                        \
        float partial = h0_ + h1_;                                              \
        _Pragma("unroll")                                                       \
        for (int off = 1; off < 64; off <<= 1)                                  \
            partial += __shfl_xor(partial, off, 64);                            \
        /* LIF scalar state (wave-uniform, redundant per lane) */               \
        syn = 0.9f * syn + partial;                                             \
        mem = 0.8f * mem + syn - spk_prev;                                      \
        const float spk = (mem > 1.0f) ? 1.0f : 0.0f;                           \
        post = 0.9f * post + spk;                                               \
        const float ap = 0.008f * spk, am = 0.0066f * post;                     \
        /* STDP into the NEXT buffer (4-deep rotation: no WAR vs young stores)*/\
        _Pragma("unroll")                                                       \
        for (int k = 0; k < 16; ++k)                                            \
            WO[k] = fminf(fmaxf(WI[k] + ap * p[k] - am * xf[k], 0.0f), 1.0f);   \
        const size_t r_  = (size_t)t * N_NEURONS + row;                         \
        const size_t ob_ = r_ * INPUT_SIZE;                                     \
        st_chunk_nt<F32>(out_v, ob_ + cofs[0], &WO[0]);                         \
        st_chunk_nt<F32>(out_v, ob_ + cofs[1], &WO[4]);                         \
        st_chunk_nt<F32>(out_v, ob_ + cofs[2], &WO[8]);                         \
        if (has4) st_chunk_nt<F32>(out_v, ob_ + cofs[3], &WO[12]);              \
        if (lane == 0) {                                                        \
            v4f sv_; sv_.x = spk; sv_.y = mem; sv_.z = syn; sv_.w = post;       \
            *(v4f*)&sbuf[wid][t & 63][0] = sv_;                                 \
        }                                                                       \
        _Pragma("unroll")                                                       \
        for (int k = 0; k < 16; ++k) p[k] = 0.9f * p[k] + xf[k];                \
        spk_prev = spk; ++t;                                                    \
    } while (0)

    for (int i = 0; i < 64; ++i) {
        const uint2 mp = msk[i][lane];       // ds_read_b64, lgkm only
        STEP(wb0, wb1, mp.x & 0xFFFFu);
        STEP(wb1, wb2, mp.x >> 16);
        STEP(wb2, wb3, mp.y & 0xFFFFu);
        STEP(wb3, wb0, mp.y >> 16);
        if ((i & 15) == 15) {                // dump 64 steps of scalar state
            const int t0 = (i - 15) * 4;
            const v4f sv = *(const v4f*)&sbuf[wid][lane][0];
            const size_t rr = (size_t)(t0 + lane) * N_NEURONS + row;
            if constexpr (F32) {
                float* out = (float*)out_v;
                out[WREC + 0 * SREC + rr] = sv.x;
                out[WREC + 1 * SREC + rr] = sv.y;
                out[WREC + 2 * SREC + rr] = sv.z;
                out[WREC + 3 * SREC + rr] = sv.w;
            } else {
                unsigned short* out = (unsigned short*)out_v;
                out[WREC + 0 * SREC + rr] = f2bf(sv.x);
                out[WREC + 1 * SREC + rr] = f2bf(sv.y);
                out[WREC + 2 * SREC + rr] = f2bf(sv.z);
                out[WREC + 3 * SREC + rr] = f2bf(sv.w);
            }
        }
    }
#undef STEP
}

__global__ __launch_bounds__(128) void snn_row_scan_kernel(
    const void* __restrict__ img,
    const void* __restrict__ W,
    void* __restrict__ out)
{
    __shared__ uint2 msk[64][64];      // 32 KB: 4 steps per entry, per lane
    __shared__ float sbuf[2][64][4];   // 2 KB: scalar-state staging per wave

    // Runtime dtype sniff (uniform): bf16 data in [0,1] never has a 16-bit
    // halfword > 0x3F80; fp32 low halfwords are random mantissa bits.
    const unsigned short* w16 = (const unsigned short*)W;
    bool f32 = false;
    for (int i = 0; i < 128; ++i) f32 |= (w16[i] > 0x3F80u);
    if (f32) scan_run<true >(img, W, out, msk, sbuf);
    else     scan_run<false>(img, W, out, msk, sbuf);
}

extern "C" void kernel_launch(void* const* d_in, const int* in_sizes, int n_in,
                              void* d_out, int out_size, void* d_ws, size_t ws_size,
                              hipStream_t stream) {
    (void)in_sizes; (void)n_in; (void)d_ws; (void)ws_size; (void)out_size;
    snn_row_scan_kernel<<<dim3(N_NEURONS / 2), dim3(128), 0, stream>>>(d_in[0], d_in[1], d_out);
}